// Round 3
// baseline (1050.818 us; speedup 1.0000x reference)
//
#include <hip/hip_runtime.h>
#include <math.h>

// R2: CNOT chains eliminated via conjugation by the linear map C (compile-time
//     XOR masks + parity sign masks); cos/sin scalarized into d_ws (read via
//     s_load, not LDS); conv window reads vectorized (float2/float4) with a
//     channel-transposed conv2 output for conv3.

#define WR_SZ 2048   // per-wave conv scratch floats (4 waves * 2048 * 4B = 32 KiB/block)
#define NL   16384   // LUT entries

// Conjugated-rotation masks. Layer k (0-based), qubit q, bit n = 7-q.
// Partner mask m = C^{-k} e_n ; role mask r = row_n(C^k).
__device__ __constant__ int QM[7][8] = {
 {0x80,0x40,0x20,0x10,0x08,0x04,0x02,0x01},
 {0xC0,0x60,0x30,0x18,0x0C,0x06,0x03,0x01},
 {0xA0,0x50,0x28,0x14,0x0A,0x05,0x02,0x01},
 {0xF0,0x78,0x3C,0x1E,0x0F,0x07,0x03,0x01},
 {0x88,0x44,0x22,0x11,0x08,0x04,0x02,0x01},
 {0xCC,0x66,0x33,0x19,0x0C,0x06,0x03,0x01},
 {0xAA,0x55,0x2A,0x15,0x0A,0x05,0x02,0x01}};
__device__ __constant__ int QR[7][8] = {
 {0x80,0x40,0x20,0x10,0x08,0x04,0x02,0x01},
 {0x80,0xC0,0xE0,0xF0,0xF8,0xFC,0xFE,0xFF},
 {0x80,0x40,0xA0,0x50,0xA8,0x54,0xAA,0x55},
 {0x80,0xC0,0x60,0x30,0x98,0xCC,0x66,0x33},
 {0x80,0x40,0x20,0x10,0x88,0x44,0x22,0x11},
 {0x80,0xC0,0xE0,0xF0,0x78,0x3C,0x1E,0x0F},
 {0x80,0x40,0xA0,0x50,0x28,0x14,0x0A,0x05}};

// ---------------- LUT builder: z(t) on a uniform grid over [-1,1], plus cos/sin ----------------
__global__ __launch_bounds__(256)
void build_lut(const float* __restrict__ w1, const float* __restrict__ b1,
               const float* __restrict__ w2, const float* __restrict__ b2,
               const float* __restrict__ w3, const float* __restrict__ b3,
               const float* __restrict__ w4, const float* __restrict__ b4,
               const float* __restrict__ w5, const float* __restrict__ b5,
               const float* __restrict__ qw,
               float* __restrict__ lut)
{
    __shared__ float hh[16][344];
    const int tid = threadIdx.x;
    const int e = tid >> 4;
    const int w = tid & 15;
    const int idx = blockIdx.x * 16 + e;
    const float t = -1.f + 2.f * (float)idx / (float)(NL - 1);

    if (blockIdx.x == 0 && tid < 56) {
        float th = 0.5f * qw[tid];
        lut[NL + tid]      = cosf(th);
        lut[NL + 56 + tid] = sinf(th);
    }

    float* hA = hh[e];
    float* hB = hA + 184;

    #pragma unroll
    for (int tt = 0; tt < 12; ++tt) {
        int j = tt * 16 + w;
        if (j < 180) hA[j] = fmaxf(fmaf(t, w1[j], b1[j]), 0.f);
    }
    for (int tt = 0; tt < 9; ++tt) {
        int j = tt * 16 + w;
        int jj = (j < 140) ? j : 0;
        const float4* wrow = (const float4*)(w2 + jj * 180);
        float a0 = 0.f, a1 = 0.f, a2 = 0.f, a3 = 0.f;
        for (int kc = 0; kc < 45; ++kc) {
            float4 h4 = *(const float4*)(hA + kc * 4);
            float4 ww = wrow[kc];
            a0 = fmaf(h4.x, ww.x, a0); a1 = fmaf(h4.y, ww.y, a1);
            a2 = fmaf(h4.z, ww.z, a2); a3 = fmaf(h4.w, ww.w, a3);
        }
        if (j < 140) hB[j] = fmaxf((a0 + a1) + (a2 + a3) + b2[j], 0.f);
    }
    for (int tt = 0; tt < 7; ++tt) {
        int j = tt * 16 + w;
        int jj = (j < 100) ? j : 0;
        const float4* wrow = (const float4*)(w3 + jj * 140);
        float a0 = 0.f, a1 = 0.f, a2 = 0.f, a3 = 0.f;
        for (int kc = 0; kc < 35; ++kc) {
            float4 h4 = *(const float4*)(hB + kc * 4);
            float4 ww = wrow[kc];
            a0 = fmaf(h4.x, ww.x, a0); a1 = fmaf(h4.y, ww.y, a1);
            a2 = fmaf(h4.z, ww.z, a2); a3 = fmaf(h4.w, ww.w, a3);
        }
        if (j < 100) hA[j] = fmaxf((a0 + a1) + (a2 + a3) + b3[j], 0.f);
    }
    for (int tt = 0; tt < 4; ++tt) {
        int j = tt * 16 + w;
        int jj = (j < 50) ? j : 0;
        const float4* wrow = (const float4*)(w4 + jj * 100);
        float a0 = 0.f, a1 = 0.f, a2 = 0.f, a3 = 0.f;
        for (int kc = 0; kc < 25; ++kc) {
            float4 h4 = *(const float4*)(hA + kc * 4);
            float4 ww = wrow[kc];
            a0 = fmaf(h4.x, ww.x, a0); a1 = fmaf(h4.y, ww.y, a1);
            a2 = fmaf(h4.z, ww.z, a2); a3 = fmaf(h4.w, ww.w, a3);
        }
        if (j < 50) hB[j] = fmaxf((a0 + a1) + (a2 + a3) + b4[j], 0.f);
    }
    float p5 = 0.f;
    for (int k = w; k < 50; k += 16) p5 = fmaf(hB[k], w5[k], p5);
    #pragma unroll
    for (int m = 1; m < 16; m <<= 1) p5 += __shfl_xor(p5, m);
    if (w == 0) lut[idx] = p5 + b5[0];
}

// ---------------- main fused kernel ----------------
__global__ __launch_bounds__(256, 5)
void fused_all(const float* __restrict__ x,
               const float* __restrict__ c1w, const float* __restrict__ c1b,
               const float* __restrict__ c2w, const float* __restrict__ c2b,
               const float* __restrict__ c3w, const float* __restrict__ c3b,
               const float* __restrict__ fcw, const float* __restrict__ fcb,
               const float* __restrict__ lut,
               float* __restrict__ out, int B)
{
    __shared__ float wreg[4][WR_SZ];

    const int tid  = threadIdx.x;
    const int lane = tid & 63;
    const int wv   = tid >> 6;

    const float* qtc = lut + NL;        // cos table (56), scalar-cached reads
    const float* qts = lut + NL + 56;   // sin table

    float* wr = wreg[wv];
    const int base = blockIdx.x * 16;

    for (int smp = 0; smp < 4; ++smp) {
        const int sample = base + wv * 4 + smp;
        if (sample >= B) break;

        float* c1p = wr;          // [0,768)    3*16*16 conv1 out (pad 1)
        float* pin = wr + 768;    // [768,1760) 31 rows x 32 cols input (pad 2)

        // zero pin (31*32=992 -> round to 1024) and c1p (768), float4 stores
        {
            float4 z4 = {0.f, 0.f, 0.f, 0.f};
            #pragma unroll
            for (int t = 0; t < 4; ++t)
                *(float4*)(pin + t * 256 + lane * 4) = z4;
            #pragma unroll
            for (int t = 0; t < 3; ++t)
                *(float4*)(c1p + t * 256 + lane * 4) = z4;
        }
        {
            const float4* xs = (const float4*)(x + (size_t)sample * 784);
            #pragma unroll
            for (int t = 0; t < 4; ++t) {
                int i4 = t * 64 + lane;
                if (i4 < 196) {
                    float4 v = xs[i4];
                    int r = i4 / 7;
                    int c = (i4 % 7) * 4;
                    float* dst = pin + (r + 2) * 32 + (c + 2);
                    dst[0] = v.x; dst[1] = v.y; dst[2] = v.z; dst[3] = v.w;
                }
            }
        }

        // ---- conv1: 1x28x28 -> 3x14x14, k5 s2 p2 (float2 window rows) ----
        #pragma unroll
        for (int t = 0; t < 4; ++t) {
            int p = t * 64 + lane;
            bool valid = p < 196;
            int pp = valid ? p : 0;
            int y = pp / 14, xx = pp % 14;
            const float* pr = pin + (2 * y) * 32 + 2 * xx;
            float win[25];
            #pragma unroll
            for (int ky = 0; ky < 5; ++ky) {
                const float* rw = pr + ky * 32;
                float2 a = *(const float2*)rw;
                float2 b = *(const float2*)(rw + 2);
                win[ky * 5 + 0] = a.x; win[ky * 5 + 1] = a.y;
                win[ky * 5 + 2] = b.x; win[ky * 5 + 3] = b.y;
                win[ky * 5 + 4] = rw[4];
            }
            #pragma unroll
            for (int c = 0; c < 3; ++c) {
                float acc = c1b[c];
                #pragma unroll
                for (int k = 0; k < 25; ++k)
                    acc = fmaf(win[k], c1w[c * 25 + k], acc);
                if (valid) c1p[c * 256 + (y + 1) * 16 + (xx + 1)] = fmaxf(acc, 0.f);
            }
        }

        // ---- conv2: 3x14x14 -> 6x7x7 -> transposed [81 pos][8 ch], k3 s2 p1 ----
        float* c2pT = wr + 768;   // [768,1416) ; pin dead
        {
            float4 z4 = {0.f, 0.f, 0.f, 0.f};
            #pragma unroll
            for (int t = 0; t < 3; ++t)   // zero [768,1536) (covers 648 used)
                *(float4*)(c2pT + t * 256 + lane * 4) = z4;
        }
        {
            int p = lane;
            bool valid = p < 49;
            int pp = valid ? p : 0;
            int y = pp / 7, xx = pp % 7;
            float acc[6];
            #pragma unroll
            for (int c = 0; c < 6; ++c) acc[c] = c2b[c];
            #pragma unroll
            for (int ic = 0; ic < 3; ++ic) {
                const float* pr = c1p + ic * 256 + (2 * y) * 16 + 2 * xx;
                float win[9];
                #pragma unroll
                for (int ky = 0; ky < 3; ++ky) {
                    const float* rw = pr + ky * 16;
                    float2 a = *(const float2*)rw;
                    win[ky * 3 + 0] = a.x; win[ky * 3 + 1] = a.y;
                    win[ky * 3 + 2] = rw[2];
                }
                #pragma unroll
                for (int c = 0; c < 6; ++c)
                    #pragma unroll
                    for (int k = 0; k < 9; ++k)
                        acc[c] = fmaf(win[k], c2w[c * 27 + ic * 9 + k], acc[c]);
            }
            if (valid) {
                float* op = c2pT + ((y + 1) * 9 + (xx + 1)) * 8;
                float2 o01 = {fmaxf(acc[0], 0.f), fmaxf(acc[1], 0.f)};
                float2 o23 = {fmaxf(acc[2], 0.f), fmaxf(acc[3], 0.f)};
                float2 o45 = {fmaxf(acc[4], 0.f), fmaxf(acc[5], 0.f)};
                *(float2*)(op + 0) = o01;
                *(float2*)(op + 2) = o23;
                *(float2*)(op + 4) = o45;
            }
        }

        // ---- conv3: 6x7x7 -> 12x7x7, k3 s1 p1 (float4+float2 channel reads) ----
        float* c3 = wr + 1416;   // [1416,2004) = 12*49
        {
            int p = lane;
            bool valid = p < 49;
            int pp = valid ? p : 0;
            int y = pp / 7, xx = pp % 7;
            float acc[12];
            #pragma unroll
            for (int c = 0; c < 12; ++c) acc[c] = c3b[c];
            #pragma unroll
            for (int dy = 0; dy < 3; ++dy)
                #pragma unroll
                for (int dx = 0; dx < 3; ++dx) {
                    const float* cp = c2pT + ((y + dy) * 9 + (xx + dx)) * 8;
                    float4 ch03 = *(const float4*)cp;
                    float2 ch45 = *(const float2*)(cp + 4);
                    const int k = dy * 3 + dx;
                    #pragma unroll
                    for (int c = 0; c < 12; ++c) {
                        const float* wp = c3w + c * 54 + k;
                        acc[c] = fmaf(ch03.x, wp[0],  acc[c]);
                        acc[c] = fmaf(ch03.y, wp[9],  acc[c]);
                        acc[c] = fmaf(ch03.z, wp[18], acc[c]);
                        acc[c] = fmaf(ch03.w, wp[27], acc[c]);
                        acc[c] = fmaf(ch45.x, wp[36], acc[c]);
                        acc[c] = fmaf(ch45.y, wp[45], acc[c]);
                    }
                }
            if (valid) {
                #pragma unroll
                for (int c = 0; c < 12; ++c)
                    c3[c * 49 + p] = fmaxf(acc[c], 0.f);
            }
        }

        // ---- adaptive pool (overlapping 4x4 bins) -> wr[0..48) ----
        {
            int o = lane;
            if (o < 48) {
                int c = o >> 2, i = (o >> 1) & 1, j = o & 1;
                int ri = i * 3, cj = j * 3;
                float s = 0.f;
                #pragma unroll
                for (int dy = 0; dy < 4; ++dy)
                    #pragma unroll
                    for (int dx = 0; dx < 4; ++dx)
                        s += c3[c * 49 + (ri + dy) * 7 + (cj + dx)];
                wr[o] = s * (1.f / 16.f);
            }
        }

        // ---- fc 48->256 + relu + L2-normalize; lane l keeps feats 4l..4l+3 ----
        float st[4];
        {
            const int o0 = lane * 4;
            const float4* wr0 = (const float4*)(fcw + (o0 + 0) * 48);
            const float4* wr1 = (const float4*)(fcw + (o0 + 1) * 48);
            const float4* wr2 = (const float4*)(fcw + (o0 + 2) * 48);
            const float4* wr3 = (const float4*)(fcw + (o0 + 3) * 48);
            float a0 = 0.f, a1 = 0.f, a2 = 0.f, a3 = 0.f;
            #pragma unroll
            for (int kc = 0; kc < 12; ++kc) {
                float4 pv = *(const float4*)(wr + kc * 4);
                float4 q0 = wr0[kc], q1 = wr1[kc], q2 = wr2[kc], q3 = wr3[kc];
                a0 = fmaf(pv.x, q0.x, a0); a0 = fmaf(pv.y, q0.y, a0);
                a0 = fmaf(pv.z, q0.z, a0); a0 = fmaf(pv.w, q0.w, a0);
                a1 = fmaf(pv.x, q1.x, a1); a1 = fmaf(pv.y, q1.y, a1);
                a1 = fmaf(pv.z, q1.z, a1); a1 = fmaf(pv.w, q1.w, a1);
                a2 = fmaf(pv.x, q2.x, a2); a2 = fmaf(pv.y, q2.y, a2);
                a2 = fmaf(pv.z, q2.z, a2); a2 = fmaf(pv.w, q2.w, a2);
                a3 = fmaf(pv.x, q3.x, a3); a3 = fmaf(pv.y, q3.y, a3);
                a3 = fmaf(pv.z, q3.z, a3); a3 = fmaf(pv.w, q3.w, a3);
            }
            float4 fb = *(const float4*)(fcb + o0);
            float v0 = fmaxf(a0 + fb.x, 0.f);
            float v1 = fmaxf(a1 + fb.y, 0.f);
            float v2 = fmaxf(a2 + fb.z, 0.f);
            float v3 = fmaxf(a3 + fb.w, 0.f);
            float ss = v0 * v0 + v1 * v1 + v2 * v2 + v3 * v3;
            #pragma unroll
            for (int m = 1; m < 64; m <<= 1) ss += __shfl_xor(ss, m);
            float scale = 1.f / fmaxf(sqrtf(ss), 1e-12f);
            st[0] = v0 * scale; st[1] = v1 * scale;
            st[2] = v2 * scale; st[3] = v3 * scale;
        }

        // ---- qsim: conjugated rotations only, no CNOTs ----
        // amp = 4*lane + j ; lane-mask = m>>2 , reg-mask = m&3
        #pragma unroll
        for (int layer = 0; layer < 7; ++layer) {
            #pragma unroll
            for (int q = 0; q < 8; ++q) {
                const int m  = QM[layer][q], r = QR[layer][q];
                const int lm = m >> 2, rm = m & 3;
                const int rl = r >> 2, rr = r & 3;
                const float c = qtc[layer * 8 + q];
                const float s = qts[layer * 8 + q];
                const float sgn = (__popc(lane & rl) & 1) ? s : -s;
                float p0 = st[0 ^ rm], p1 = st[1 ^ rm];
                float p2 = st[2 ^ rm], p3 = st[3 ^ rm];
                if (lm) {
                    p0 = __shfl_xor(p0, lm); p1 = __shfl_xor(p1, lm);
                    p2 = __shfl_xor(p2, lm); p3 = __shfl_xor(p3, lm);
                }
                const float s0 = sgn;
                const float s1 = (__popc(1 & rr) & 1) ? -sgn : sgn;
                const float s2 = (__popc(2 & rr) & 1) ? -sgn : sgn;
                const float s3 = (__popc(3 & rr) & 1) ? -sgn : sgn;
                st[0] = fmaf(c, st[0], s0 * p0);
                st[1] = fmaf(c, st[1], s1 * p1);
                st[2] = fmaf(c, st[2], s2 * p2);
                st[3] = fmaf(c, st[3], s3 * p3);
            }
        }

        // ---- measurement: bit7 = lane bit5 (invariant under trailing C^7) ----
        float part = st[0] * st[0] + st[1] * st[1] + st[2] * st[2] + st[3] * st[3];
        part = (lane & 32) ? -part : part;
        #pragma unroll
        for (int m = 1; m < 64; m <<= 1) part += __shfl_xor(part, m);

        if (lane == 0) {
            float qout = part;
            float u = (qout + 1.f) * 0.5f * (float)(NL - 1);
            int i0 = (int)floorf(u);
            i0 = (i0 < 0) ? 0 : ((i0 > NL - 2) ? NL - 2 : i0);
            float fr = u - (float)i0;
            float z0 = lut[i0], z1 = lut[i0 + 1];
            float z = fmaf(z1 - z0, fr, z0);
            out[sample] = 1.f / (1.f + expf(-z));
        }
    }
}

extern "C" void kernel_launch(void* const* d_in, const int* in_sizes, int n_in,
                              void* d_out, int out_size, void* d_ws, size_t ws_size,
                              hipStream_t stream) {
    const float* x   = (const float*)d_in[0];
    const float* c1w = (const float*)d_in[1];
    const float* c1b = (const float*)d_in[2];
    const float* c2w = (const float*)d_in[3];
    const float* c2b = (const float*)d_in[4];
    const float* c3w = (const float*)d_in[5];
    const float* c3b = (const float*)d_in[6];
    const float* fcw = (const float*)d_in[7];
    const float* fcb = (const float*)d_in[8];
    const float* qw  = (const float*)d_in[9];
    const float* w1  = (const float*)d_in[10];
    const float* b1  = (const float*)d_in[11];
    const float* w2  = (const float*)d_in[12];
    const float* b2  = (const float*)d_in[13];
    const float* w3  = (const float*)d_in[14];
    const float* b3  = (const float*)d_in[15];
    const float* w4  = (const float*)d_in[16];
    const float* b4  = (const float*)d_in[17];
    const float* w5  = (const float*)d_in[18];
    const float* b5  = (const float*)d_in[19];

    float* lut = (float*)d_ws;   // NL z-values + 112 cos/sin

    build_lut<<<dim3(NL / 16), dim3(256), 0, stream>>>(
        w1, b1, w2, b2, w3, b3, w4, b4, w5, b5, qw, lut);

    int B = in_sizes[0] / 784;
    int grid = (B + 15) / 16;
    fused_all<<<dim3(grid), dim3(256), 0, stream>>>(
        x, c1w, c1b, c2w, c2b, c3w, c3b, fcw, fcb, lut,
        (float*)d_out, B);
}

// Round 4
// 713.855 us; speedup vs baseline: 1.4720x; 1.4720x over previous
//
#include <hip/hip_runtime.h>
#include <math.h>

// R3: R2's CNOT-free conjugated qsim, but with mask tables as constexpr and
//     rotation steps macro-expanded so ALL st[] indices / shuffle masks / sign
//     flips are compile-time literals (R2 put st[] in scratch via runtime
//     indices loaded from __constant__ memory -> +400 MB HBM traffic).

#define WR_SZ 2048   // per-wave conv scratch floats (4 waves * 2048 * 4B = 32 KiB/block)
#define NL   16384   // LUT entries

// Conjugated-rotation masks. Layer k (0-based), qubit q, bit n = 7-q.
// Partner mask m = C^{-k} e_n ; role mask r = row_n(C^k).  (verified R2: absmax 0.0)
constexpr int QM[7][8] = {
 {0x80,0x40,0x20,0x10,0x08,0x04,0x02,0x01},
 {0xC0,0x60,0x30,0x18,0x0C,0x06,0x03,0x01},
 {0xA0,0x50,0x28,0x14,0x0A,0x05,0x02,0x01},
 {0xF0,0x78,0x3C,0x1E,0x0F,0x07,0x03,0x01},
 {0x88,0x44,0x22,0x11,0x08,0x04,0x02,0x01},
 {0xCC,0x66,0x33,0x19,0x0C,0x06,0x03,0x01},
 {0xAA,0x55,0x2A,0x15,0x0A,0x05,0x02,0x01}};
constexpr int QR[7][8] = {
 {0x80,0x40,0x20,0x10,0x08,0x04,0x02,0x01},
 {0x80,0xC0,0xE0,0xF0,0xF8,0xFC,0xFE,0xFF},
 {0x80,0x40,0xA0,0x50,0xA8,0x54,0xAA,0x55},
 {0x80,0xC0,0x60,0x30,0x98,0xCC,0x66,0x33},
 {0x80,0x40,0x20,0x10,0x88,0x44,0x22,0x11},
 {0x80,0xC0,0xE0,0xF0,0x78,0x3C,0x1E,0x0F},
 {0x80,0x40,0xA0,0x50,0x28,0x14,0x0A,0x05}};

// One conjugated rotation, fully compile-time-specialized.
#define ROTSTEP(L, Q) { \
    constexpr int m_  = QM[L][Q]; \
    constexpr int r_  = QR[L][Q]; \
    constexpr int lm_ = m_ >> 2, rm_ = m_ & 3; \
    constexpr int rl_ = r_ >> 2, rr_ = r_ & 3; \
    constexpr float f1_ = (rr_ & 1) ? -1.f : 1.f; \
    constexpr float f2_ = (rr_ & 2) ? -1.f : 1.f; \
    constexpr float f3_ = f1_ * f2_; \
    const float c_ = qtc[(L) * 8 + (Q)]; \
    const float s_ = qts[(L) * 8 + (Q)]; \
    float sgn_; \
    if constexpr (rl_ != 0) sgn_ = (__popc(lane & rl_) & 1) ? s_ : -s_; \
    else                    sgn_ = -s_; \
    float p0_ = st[0 ^ rm_], p1_ = st[1 ^ rm_]; \
    float p2_ = st[2 ^ rm_], p3_ = st[3 ^ rm_]; \
    if constexpr (lm_ != 0) { \
        p0_ = __shfl_xor(p0_, lm_); p1_ = __shfl_xor(p1_, lm_); \
        p2_ = __shfl_xor(p2_, lm_); p3_ = __shfl_xor(p3_, lm_); \
    } \
    st[0] = fmaf(c_, st[0], sgn_ * p0_); \
    st[1] = fmaf(c_, st[1], (f1_ * sgn_) * p1_); \
    st[2] = fmaf(c_, st[2], (f2_ * sgn_) * p2_); \
    st[3] = fmaf(c_, st[3], (f3_ * sgn_) * p3_); \
}

#define ROTLAYER(L) \
    ROTSTEP(L,0) ROTSTEP(L,1) ROTSTEP(L,2) ROTSTEP(L,3) \
    ROTSTEP(L,4) ROTSTEP(L,5) ROTSTEP(L,6) ROTSTEP(L,7)

// ---------------- LUT builder: z(t) on a uniform grid over [-1,1], plus cos/sin ----------------
__global__ __launch_bounds__(256)
void build_lut(const float* __restrict__ w1, const float* __restrict__ b1,
               const float* __restrict__ w2, const float* __restrict__ b2,
               const float* __restrict__ w3, const float* __restrict__ b3,
               const float* __restrict__ w4, const float* __restrict__ b4,
               const float* __restrict__ w5, const float* __restrict__ b5,
               const float* __restrict__ qw,
               float* __restrict__ lut)
{
    __shared__ float hh[16][344];
    const int tid = threadIdx.x;
    const int e = tid >> 4;
    const int w = tid & 15;
    const int idx = blockIdx.x * 16 + e;
    const float t = -1.f + 2.f * (float)idx / (float)(NL - 1);

    if (blockIdx.x == 0 && tid < 56) {
        float th = 0.5f * qw[tid];
        lut[NL + tid]      = cosf(th);
        lut[NL + 56 + tid] = sinf(th);
    }

    float* hA = hh[e];
    float* hB = hA + 184;

    #pragma unroll
    for (int tt = 0; tt < 12; ++tt) {
        int j = tt * 16 + w;
        if (j < 180) hA[j] = fmaxf(fmaf(t, w1[j], b1[j]), 0.f);
    }
    for (int tt = 0; tt < 9; ++tt) {
        int j = tt * 16 + w;
        int jj = (j < 140) ? j : 0;
        const float4* wrow = (const float4*)(w2 + jj * 180);
        float a0 = 0.f, a1 = 0.f, a2 = 0.f, a3 = 0.f;
        for (int kc = 0; kc < 45; ++kc) {
            float4 h4 = *(const float4*)(hA + kc * 4);
            float4 ww = wrow[kc];
            a0 = fmaf(h4.x, ww.x, a0); a1 = fmaf(h4.y, ww.y, a1);
            a2 = fmaf(h4.z, ww.z, a2); a3 = fmaf(h4.w, ww.w, a3);
        }
        if (j < 140) hB[j] = fmaxf((a0 + a1) + (a2 + a3) + b2[j], 0.f);
    }
    for (int tt = 0; tt < 7; ++tt) {
        int j = tt * 16 + w;
        int jj = (j < 100) ? j : 0;
        const float4* wrow = (const float4*)(w3 + jj * 140);
        float a0 = 0.f, a1 = 0.f, a2 = 0.f, a3 = 0.f;
        for (int kc = 0; kc < 35; ++kc) {
            float4 h4 = *(const float4*)(hB + kc * 4);
            float4 ww = wrow[kc];
            a0 = fmaf(h4.x, ww.x, a0); a1 = fmaf(h4.y, ww.y, a1);
            a2 = fmaf(h4.z, ww.z, a2); a3 = fmaf(h4.w, ww.w, a3);
        }
        if (j < 100) hA[j] = fmaxf((a0 + a1) + (a2 + a3) + b3[j], 0.f);
    }
    for (int tt = 0; tt < 4; ++tt) {
        int j = tt * 16 + w;
        int jj = (j < 50) ? j : 0;
        const float4* wrow = (const float4*)(w4 + jj * 100);
        float a0 = 0.f, a1 = 0.f, a2 = 0.f, a3 = 0.f;
        for (int kc = 0; kc < 25; ++kc) {
            float4 h4 = *(const float4*)(hA + kc * 4);
            float4 ww = wrow[kc];
            a0 = fmaf(h4.x, ww.x, a0); a1 = fmaf(h4.y, ww.y, a1);
            a2 = fmaf(h4.z, ww.z, a2); a3 = fmaf(h4.w, ww.w, a3);
        }
        if (j < 50) hB[j] = fmaxf((a0 + a1) + (a2 + a3) + b4[j], 0.f);
    }
    float p5 = 0.f;
    for (int k = w; k < 50; k += 16) p5 = fmaf(hB[k], w5[k], p5);
    #pragma unroll
    for (int m = 1; m < 16; m <<= 1) p5 += __shfl_xor(p5, m);
    if (w == 0) lut[idx] = p5 + b5[0];
}

// ---------------- main fused kernel ----------------
__global__ __launch_bounds__(256, 5)
void fused_all(const float* __restrict__ x,
               const float* __restrict__ c1w, const float* __restrict__ c1b,
               const float* __restrict__ c2w, const float* __restrict__ c2b,
               const float* __restrict__ c3w, const float* __restrict__ c3b,
               const float* __restrict__ fcw, const float* __restrict__ fcb,
               const float* __restrict__ lut,
               float* __restrict__ out, int B)
{
    __shared__ float wreg[4][WR_SZ];

    const int tid  = threadIdx.x;
    const int lane = tid & 63;
    const int wv   = tid >> 6;

    const float* qtc = lut + NL;        // cos table (56), wave-uniform s_load reads
    const float* qts = lut + NL + 56;   // sin table

    float* wr = wreg[wv];
    const int base = blockIdx.x * 16;

    for (int smp = 0; smp < 4; ++smp) {
        const int sample = base + wv * 4 + smp;
        if (sample >= B) break;

        float* c1p = wr;          // [0,768)    3*16*16 conv1 out (pad 1)
        float* pin = wr + 768;    // [768,1760) 31 rows x 32 cols input (pad 2)

        {
            float4 z4 = {0.f, 0.f, 0.f, 0.f};
            #pragma unroll
            for (int t = 0; t < 4; ++t)
                *(float4*)(pin + t * 256 + lane * 4) = z4;
            #pragma unroll
            for (int t = 0; t < 3; ++t)
                *(float4*)(c1p + t * 256 + lane * 4) = z4;
        }
        {
            const float4* xs = (const float4*)(x + (size_t)sample * 784);
            #pragma unroll
            for (int t = 0; t < 4; ++t) {
                int i4 = t * 64 + lane;
                if (i4 < 196) {
                    float4 v = xs[i4];
                    int r = i4 / 7;
                    int c = (i4 % 7) * 4;
                    float* dst = pin + (r + 2) * 32 + (c + 2);
                    dst[0] = v.x; dst[1] = v.y; dst[2] = v.z; dst[3] = v.w;
                }
            }
        }

        // ---- conv1: 1x28x28 -> 3x14x14, k5 s2 p2 (float2 window rows) ----
        #pragma unroll
        for (int t = 0; t < 4; ++t) {
            int p = t * 64 + lane;
            bool valid = p < 196;
            int pp = valid ? p : 0;
            int y = pp / 14, xx = pp % 14;
            const float* pr = pin + (2 * y) * 32 + 2 * xx;
            float win[25];
            #pragma unroll
            for (int ky = 0; ky < 5; ++ky) {
                const float* rw = pr + ky * 32;
                float2 a = *(const float2*)rw;
                float2 b = *(const float2*)(rw + 2);
                win[ky * 5 + 0] = a.x; win[ky * 5 + 1] = a.y;
                win[ky * 5 + 2] = b.x; win[ky * 5 + 3] = b.y;
                win[ky * 5 + 4] = rw[4];
            }
            #pragma unroll
            for (int c = 0; c < 3; ++c) {
                float acc = c1b[c];
                #pragma unroll
                for (int k = 0; k < 25; ++k)
                    acc = fmaf(win[k], c1w[c * 25 + k], acc);
                if (valid) c1p[c * 256 + (y + 1) * 16 + (xx + 1)] = fmaxf(acc, 0.f);
            }
        }

        // ---- conv2: 3x14x14 -> 6x7x7 -> transposed [81 pos][8 ch], k3 s2 p1 ----
        float* c2pT = wr + 768;   // [768,1416) ; pin dead
        {
            float4 z4 = {0.f, 0.f, 0.f, 0.f};
            #pragma unroll
            for (int t = 0; t < 3; ++t)
                *(float4*)(c2pT + t * 256 + lane * 4) = z4;
        }
        {
            int p = lane;
            bool valid = p < 49;
            int pp = valid ? p : 0;
            int y = pp / 7, xx = pp % 7;
            float acc[6];
            #pragma unroll
            for (int c = 0; c < 6; ++c) acc[c] = c2b[c];
            #pragma unroll
            for (int ic = 0; ic < 3; ++ic) {
                const float* pr = c1p + ic * 256 + (2 * y) * 16 + 2 * xx;
                float win[9];
                #pragma unroll
                for (int ky = 0; ky < 3; ++ky) {
                    const float* rw = pr + ky * 16;
                    float2 a = *(const float2*)rw;
                    win[ky * 3 + 0] = a.x; win[ky * 3 + 1] = a.y;
                    win[ky * 3 + 2] = rw[2];
                }
                #pragma unroll
                for (int c = 0; c < 6; ++c)
                    #pragma unroll
                    for (int k = 0; k < 9; ++k)
                        acc[c] = fmaf(win[k], c2w[c * 27 + ic * 9 + k], acc[c]);
            }
            if (valid) {
                float* op = c2pT + ((y + 1) * 9 + (xx + 1)) * 8;
                float2 o01 = {fmaxf(acc[0], 0.f), fmaxf(acc[1], 0.f)};
                float2 o23 = {fmaxf(acc[2], 0.f), fmaxf(acc[3], 0.f)};
                float2 o45 = {fmaxf(acc[4], 0.f), fmaxf(acc[5], 0.f)};
                *(float2*)(op + 0) = o01;
                *(float2*)(op + 2) = o23;
                *(float2*)(op + 4) = o45;
            }
        }

        // ---- conv3: 6x7x7 -> 12x7x7, k3 s1 p1 (float4+float2 channel reads) ----
        float* c3 = wr + 1416;   // [1416,2004) = 12*49
        {
            int p = lane;
            bool valid = p < 49;
            int pp = valid ? p : 0;
            int y = pp / 7, xx = pp % 7;
            float acc[12];
            #pragma unroll
            for (int c = 0; c < 12; ++c) acc[c] = c3b[c];
            #pragma unroll
            for (int dy = 0; dy < 3; ++dy)
                #pragma unroll
                for (int dx = 0; dx < 3; ++dx) {
                    const float* cp = c2pT + ((y + dy) * 9 + (xx + dx)) * 8;
                    float4 ch03 = *(const float4*)cp;
                    float2 ch45 = *(const float2*)(cp + 4);
                    const int k = dy * 3 + dx;
                    #pragma unroll
                    for (int c = 0; c < 12; ++c) {
                        const float* wp = c3w + c * 54 + k;
                        acc[c] = fmaf(ch03.x, wp[0],  acc[c]);
                        acc[c] = fmaf(ch03.y, wp[9],  acc[c]);
                        acc[c] = fmaf(ch03.z, wp[18], acc[c]);
                        acc[c] = fmaf(ch03.w, wp[27], acc[c]);
                        acc[c] = fmaf(ch45.x, wp[36], acc[c]);
                        acc[c] = fmaf(ch45.y, wp[45], acc[c]);
                    }
                }
            if (valid) {
                #pragma unroll
                for (int c = 0; c < 12; ++c)
                    c3[c * 49 + p] = fmaxf(acc[c], 0.f);
            }
        }

        // ---- adaptive pool (overlapping 4x4 bins) -> wr[0..48) ----
        {
            int o = lane;
            if (o < 48) {
                int c = o >> 2, i = (o >> 1) & 1, j = o & 1;
                int ri = i * 3, cj = j * 3;
                float s = 0.f;
                #pragma unroll
                for (int dy = 0; dy < 4; ++dy)
                    #pragma unroll
                    for (int dx = 0; dx < 4; ++dx)
                        s += c3[c * 49 + (ri + dy) * 7 + (cj + dx)];
                wr[o] = s * (1.f / 16.f);
            }
        }

        // ---- fc 48->256 + relu + L2-normalize; lane l keeps feats 4l..4l+3 ----
        float st[4];
        {
            const int o0 = lane * 4;
            const float4* wr0 = (const float4*)(fcw + (o0 + 0) * 48);
            const float4* wr1 = (const float4*)(fcw + (o0 + 1) * 48);
            const float4* wr2 = (const float4*)(fcw + (o0 + 2) * 48);
            const float4* wr3 = (const float4*)(fcw + (o0 + 3) * 48);
            float a0 = 0.f, a1 = 0.f, a2 = 0.f, a3 = 0.f;
            #pragma unroll
            for (int kc = 0; kc < 12; ++kc) {
                float4 pv = *(const float4*)(wr + kc * 4);
                float4 q0 = wr0[kc], q1 = wr1[kc], q2 = wr2[kc], q3 = wr3[kc];
                a0 = fmaf(pv.x, q0.x, a0); a0 = fmaf(pv.y, q0.y, a0);
                a0 = fmaf(pv.z, q0.z, a0); a0 = fmaf(pv.w, q0.w, a0);
                a1 = fmaf(pv.x, q1.x, a1); a1 = fmaf(pv.y, q1.y, a1);
                a1 = fmaf(pv.z, q1.z, a1); a1 = fmaf(pv.w, q1.w, a1);
                a2 = fmaf(pv.x, q2.x, a2); a2 = fmaf(pv.y, q2.y, a2);
                a2 = fmaf(pv.z, q2.z, a2); a2 = fmaf(pv.w, q2.w, a2);
                a3 = fmaf(pv.x, q3.x, a3); a3 = fmaf(pv.y, q3.y, a3);
                a3 = fmaf(pv.z, q3.z, a3); a3 = fmaf(pv.w, q3.w, a3);
            }
            float4 fb = *(const float4*)(fcb + o0);
            float v0 = fmaxf(a0 + fb.x, 0.f);
            float v1 = fmaxf(a1 + fb.y, 0.f);
            float v2 = fmaxf(a2 + fb.z, 0.f);
            float v3 = fmaxf(a3 + fb.w, 0.f);
            float ss = v0 * v0 + v1 * v1 + v2 * v2 + v3 * v3;
            #pragma unroll
            for (int m = 1; m < 64; m <<= 1) ss += __shfl_xor(ss, m);
            float scale = 1.f / fmaxf(sqrtf(ss), 1e-12f);
            st[0] = v0 * scale; st[1] = v1 * scale;
            st[2] = v2 * scale; st[3] = v3 * scale;
        }

        // ---- qsim: 56 conjugated rotations, no CNOTs, all masks literal ----
        ROTLAYER(0) ROTLAYER(1) ROTLAYER(2) ROTLAYER(3)
        ROTLAYER(4) ROTLAYER(5) ROTLAYER(6)

        // ---- measurement: bit7 = lane bit5 (invariant under trailing C^7) ----
        float part = st[0] * st[0] + st[1] * st[1] + st[2] * st[2] + st[3] * st[3];
        part = (lane & 32) ? -part : part;
        #pragma unroll
        for (int m = 1; m < 64; m <<= 1) part += __shfl_xor(part, m);

        if (lane == 0) {
            float qout = part;
            float u = (qout + 1.f) * 0.5f * (float)(NL - 1);
            int i0 = (int)floorf(u);
            i0 = (i0 < 0) ? 0 : ((i0 > NL - 2) ? NL - 2 : i0);
            float fr = u - (float)i0;
            float z0 = lut[i0], z1 = lut[i0 + 1];
            float z = fmaf(z1 - z0, fr, z0);
            out[sample] = 1.f / (1.f + expf(-z));
        }
    }
}

extern "C" void kernel_launch(void* const* d_in, const int* in_sizes, int n_in,
                              void* d_out, int out_size, void* d_ws, size_t ws_size,
                              hipStream_t stream) {
    const float* x   = (const float*)d_in[0];
    const float* c1w = (const float*)d_in[1];
    const float* c1b = (const float*)d_in[2];
    const float* c2w = (const float*)d_in[3];
    const float* c2b = (const float*)d_in[4];
    const float* c3w = (const float*)d_in[5];
    const float* c3b = (const float*)d_in[6];
    const float* fcw = (const float*)d_in[7];
    const float* fcb = (const float*)d_in[8];
    const float* qw  = (const float*)d_in[9];
    const float* w1  = (const float*)d_in[10];
    const float* b1  = (const float*)d_in[11];
    const float* w2  = (const float*)d_in[12];
    const float* b2  = (const float*)d_in[13];
    const float* w3  = (const float*)d_in[14];
    const float* b3  = (const float*)d_in[15];
    const float* w4  = (const float*)d_in[16];
    const float* b4  = (const float*)d_in[17];
    const float* w5  = (const float*)d_in[18];
    const float* b5  = (const float*)d_in[19];

    float* lut = (float*)d_ws;   // NL z-values + 112 cos/sin

    build_lut<<<dim3(NL / 16), dim3(256), 0, stream>>>(
        w1, b1, w2, b2, w3, b3, w4, b4, w5, b5, qw, lut);

    int B = in_sizes[0] / 784;
    int grid = (B + 15) / 16;
    fused_all<<<dim3(grid), dim3(256), 0, stream>>>(
        x, c1w, c1b, c2w, c2b, c3w, c3b, fcw, fcb, lut,
        (float*)d_out, B);
}